// Round 17
// baseline (180.908 us; speedup 1.0000x reference)
//
#include <hip/hip_runtime.h>
#include <math.h>

#define BATCH 32
#define NC    1024
#define NHID  512
#define NH    56
#define NW    56
#define HWSZ  3136   // 56*56
#define HW4   784    // HWSZ/4 (= 56 rows * 14 float4/row)

typedef float nfloat4 __attribute__((ext_vector_type(4)));

__device__ __forceinline__ float gelu_exact(float x) {
    return 0.5f * x * (1.0f + erff(x * 0.7071067811865476f));
}

// ---------------------------------------------------------------------------
// Kernel 1: GAP. One WAVE per (b,c) row. MEASURED: 59.8 us = 6.9 TB/s (read
// ceiling). Do not touch.
// ---------------------------------------------------------------------------
__global__ __launch_bounds__(256) void gap_kernel(const float* __restrict__ x,
                                                  float* __restrict__ y) {
    const int row  = (blockIdx.x << 2) | (threadIdx.x >> 6); // 4 waves/block
    const int lane = threadIdx.x & 63;
    const nfloat4* xr = (const nfloat4*)(x + (size_t)row * HWSZ);

    float s = 0.f;
#pragma unroll
    for (int it = 0; it < 12; ++it) {
        nfloat4 v = __builtin_nontemporal_load(xr + lane + (it << 6));
        s += (v.x + v.y) + (v.z + v.w);
    }
    if (lane < 16) {
        nfloat4 v = __builtin_nontemporal_load(xr + 768 + lane);
        s += (v.x + v.y) + (v.z + v.w);
    }
#pragma unroll
    for (int off = 32; off > 0; off >>= 1) s += __shfl_down(s, off);
    if (lane == 0) y[row] = s * (1.0f / 3136.0f);
}

// ---------------------------------------------------------------------------
// Kernel 2: fc1 — h = gelu(y @ W1). Grid (16,32)=512 blocks, 32 cols/block,
// 32-way split-K. jc==0 blocks also (re-)seed AB with the biases — this
// OVERWRITES any prior accumulation, making the (fc1,fc2ab) pair idempotent.
// ---------------------------------------------------------------------------
__global__ __launch_bounds__(256) void fc1_kernel(const float* __restrict__ y,
                                                  const float* __restrict__ W1,
                                                  const float* __restrict__ bA,
                                                  const float* __restrict__ bB,
                                                  float* __restrict__ h,
                                                  float* __restrict__ AB) {
    const int jc = blockIdx.x;   // 0..15
    const int b  = blockIdx.y;   // 0..31
    const int t  = threadIdx.x;

    __shared__ float   sy[NC];
    __shared__ nfloat4 part[256];
    __shared__ nfloat4 spart[64];
    for (int i = t; i < NC; i += 256) sy[i] = y[b * NC + i];
    __syncthreads();

    const int lane8 = t & 7;
    const int j0 = jc * 32 + lane8 * 4;
    const int ks = (t >> 3) * 32;            // 32 K-slices of 32 rows

    nfloat4 acc0 = {0.f, 0.f, 0.f, 0.f};
    nfloat4 acc1 = {0.f, 0.f, 0.f, 0.f};
    const float* wbase = W1 + (size_t)ks * NHID + j0;
#pragma unroll 8
    for (int c = 0; c < 32; c += 2) {
        nfloat4 w0 = *(const nfloat4*)(wbase + (size_t)(c + 0) * NHID);
        nfloat4 w1 = *(const nfloat4*)(wbase + (size_t)(c + 1) * NHID);
        acc0 += sy[ks + c + 0] * w0;
        acc1 += sy[ks + c + 1] * w1;
    }
    part[t] = acc0 + acc1;
    __syncthreads();
    if (t < 64) spart[t] = part[t] + part[t + 64] + part[t + 128] + part[t + 192];
    __syncthreads();
    if (t < 8) {
        nfloat4 s = spart[t];
#pragma unroll
        for (int g = 1; g < 8; ++g) s += spart[g * 8 + t];
        float* hp = h + b * NHID + jc * 32 + t * 4;
        hp[0] = gelu_exact(s.x);
        hp[1] = gelu_exact(s.y);
        hp[2] = gelu_exact(s.z);
        hp[3] = gelu_exact(s.w);
    }
    if (jc == 0) {                       // (re-)seed AB with biases
        if (t < NH)                         AB[b * 128 + t]      = bA[t];
        else if (t >= 64 && t < 64 + NW)    AB[b * 128 + t]      = bB[t - 64];
    }
}

// ---------------------------------------------------------------------------
// Kernel 3: fc2+ab fused. Grid (32,32)=1024 blocks, 32 yp-cols/block.
// ---------------------------------------------------------------------------
__global__ __launch_bounds__(256) void fc2ab_kernel(const float* __restrict__ h,
                                                    const float* __restrict__ W2,
                                                    const float* __restrict__ WA,
                                                    const float* __restrict__ WB,
                                                    float* __restrict__ AB) {
    const int cc = blockIdx.x;   // 0..31
    const int b  = blockIdx.y;
    const int t  = threadIdx.x;

    __shared__ float   sh[NHID];
    __shared__ nfloat4 part[256];
    __shared__ nfloat4 spart[64];
    __shared__ float   ypl[32];
    for (int i = t; i < NHID; i += 256) sh[i] = h[b * NHID + i];
    __syncthreads();

    const int lane8 = t & 7;
    const int c0 = cc * 32 + lane8 * 4;
    const int js = (t >> 3) * 16;            // 32 K-slices of 16 rows

    nfloat4 acc0 = {0.f, 0.f, 0.f, 0.f};
    nfloat4 acc1 = {0.f, 0.f, 0.f, 0.f};
    const float* wbase = W2 + (size_t)js * NC + c0;
#pragma unroll 8
    for (int jj = 0; jj < 16; jj += 2) {
        nfloat4 w0 = *(const nfloat4*)(wbase + (size_t)(jj + 0) * NC);
        nfloat4 w1 = *(const nfloat4*)(wbase + (size_t)(jj + 1) * NC);
        acc0 += sh[js + jj + 0] * w0;
        acc1 += sh[js + jj + 1] * w1;
    }
    part[t] = acc0 + acc1;
    __syncthreads();
    if (t < 64) spart[t] = part[t] + part[t + 64] + part[t + 128] + part[t + 192];
    __syncthreads();
    if (t < 8) {
        nfloat4 s = spart[t];
        #pragma unroll
        for (int g = 1; g < 8; ++g) s += spart[g * 8 + t];
        ypl[t * 4 + 0] = gelu_exact(s.x);
        ypl[t * 4 + 1] = gelu_exact(s.y);
        ypl[t * 4 + 2] = gelu_exact(s.z);
        ypl[t * 4 + 3] = gelu_exact(s.w);
    }
    __syncthreads();

    // ab partial over rows [cc*32, cc*32+32)
    if (t < 112) {
        const bool isA = t < 56;
        const int  i   = isA ? t : t - 56;
        const float* w = (isA ? WA : WB) + (size_t)(cc * 32) * 56 + i;
        float a0 = 0.f, a1 = 0.f, a2 = 0.f, a3 = 0.f;
#pragma unroll 4
        for (int c = 0; c < 32; c += 4) {
            a0 += ypl[c + 0] * w[(size_t)(c + 0) * 56];
            a1 += ypl[c + 1] * w[(size_t)(c + 1) * 56];
            a2 += ypl[c + 2] * w[(size_t)(c + 2) * 56];
            a3 += ypl[c + 3] * w[(size_t)(c + 3) * 56];
        }
        atomicAdd(&AB[b * 128 + (isA ? i : 64 + i)], (a0 + a1) + (a2 + a3));
    }
}

// ---------------------------------------------------------------------------
// Kernel 4: bcast v4 (byte-identical to R16's 160.0 config).
// ---------------------------------------------------------------------------
__global__ __launch_bounds__(256) void bcast_kernel(const float* __restrict__ AB,
                                                    float* __restrict__ out) {
    const int blk = blockIdx.x;      // 32 b * 16 chunks = 512
    const int b = blk >> 4;
    const int chunk = blk & 15;      // 64 channels per chunk
    const int t = threadIdx.x;

    __shared__ float sA[NH];
    __shared__ float sB[NW];
    __shared__ nfloat4 smap[HW4 + 64];   // 848 entries
    if (t < NH) sA[t] = AB[b * 128 + t];
    else if (t >= 64 && t < 64 + NW) sB[t - 64] = AB[b * 128 + t];
    __syncthreads();

    for (int idx = t; idx < HW4 + 64; idx += 256) {
        const int p  = (idx >= HW4) ? idx - HW4 : idx;
        const int r  = p / 14;
        const int cb = (p - r * 14) * 4;
        const float a = sA[r];
        nfloat4 q;
        q.x = 1.0f / (1.0f + expf(-(a * sB[cb + 0])));
        q.y = 1.0f / (1.0f + expf(-(a * sB[cb + 1])));
        q.z = 1.0f / (1.0f + expf(-(a * sB[cb + 2])));
        q.w = 1.0f / (1.0f + expf(-(a * sB[cb + 3])));
        smap[idx] = q;
    }
    __syncthreads();

    const int w    = t >> 6;         // wave 0..3 -> 16 channels each
    const int lane = t & 63;
    nfloat4* op = (nfloat4*)out +
                  ((size_t)b * NC + (size_t)chunk * 64 + (size_t)w * 16) * HW4;
    int pos = 0;                      // (it*64) % 784
#pragma unroll 7
    for (int it = 0; it < 196; ++it) {
        __builtin_nontemporal_store(smap[pos + lane], &op[it * 64 + lane]);
        pos += 64;
        if (pos >= HW4) pos -= HW4;
    }
}

// ---------------------------------------------------------------------------
extern "C" void kernel_launch(void* const* d_in, const int* in_sizes, int n_in,
                              void* d_out, int out_size, void* d_ws, size_t ws_size,
                              hipStream_t stream) {
    const float* x  = (const float*)d_in[0];
    const float* W1 = (const float*)d_in[1];
    const float* W2 = (const float*)d_in[2];
    const float* WA = (const float*)d_in[3];
    const float* bA = (const float*)d_in[4];
    const float* WB = (const float*)d_in[5];
    const float* bB = (const float*)d_in[6];
    float* out = (float*)d_out;

    float* y  = (float*)d_ws;            // BATCH*NC floats
    float* h  = y + BATCH * NC;          // BATCH*NHID floats
    float* AB = h + BATCH * NHID;        // BATCH*128 floats

    gap_kernel<<<BATCH * NC / 4, 256, 0, stream>>>(x, y);
    // BISECT: MLP pair launched 3x. fc1 re-seeds AB (overwrite), fc2ab
    // re-accumulates -> final pair determines AB; idempotent+deterministic.
    // Marginal = 2 x in-context MLP-pair cost. Remove after measurement.
    fc1_kernel<<<dim3(16, BATCH), 256, 0, stream>>>(y, W1, bA, bB, h, AB);
    fc2ab_kernel<<<dim3(32, BATCH), 256, 0, stream>>>(h, W2, WA, WB, AB);
    fc1_kernel<<<dim3(16, BATCH), 256, 0, stream>>>(y, W1, bA, bB, h, AB);
    fc2ab_kernel<<<dim3(32, BATCH), 256, 0, stream>>>(h, W2, WA, WB, AB);
    fc1_kernel<<<dim3(16, BATCH), 256, 0, stream>>>(y, W1, bA, bB, h, AB);
    fc2ab_kernel<<<dim3(32, BATCH), 256, 0, stream>>>(h, W2, WA, WB, AB);
    bcast_kernel<<<512, 256, 0, stream>>>(AB, out);
}

// Round 18
// 159.149 us; speedup vs baseline: 1.1367x; 1.1367x over previous
//
#include <hip/hip_runtime.h>
#include <math.h>

#define BATCH 32
#define NC    1024
#define NHID  512
#define NH    56
#define NW    56
#define HWSZ  3136   // 56*56
#define HW4   784    // HWSZ/4 (= 56 rows * 14 float4/row)

typedef float nfloat4 __attribute__((ext_vector_type(4)));

__device__ __forceinline__ float gelu_exact(float x) {
    return 0.5f * x * (1.0f + erff(x * 0.7071067811865476f));
}

// ---------------------------------------------------------------------------
// Kernel 1: GAP. One WAVE per (b,c) row. MEASURED: 59.8 us = 6.9 TB/s (read
// ceiling, bisect-proven R10). Do not touch.
// ---------------------------------------------------------------------------
__global__ __launch_bounds__(256) void gap_kernel(const float* __restrict__ x,
                                                  float* __restrict__ y) {
    const int row  = (blockIdx.x << 2) | (threadIdx.x >> 6); // 4 waves/block
    const int lane = threadIdx.x & 63;
    const nfloat4* xr = (const nfloat4*)(x + (size_t)row * HWSZ);

    float s = 0.f;
#pragma unroll
    for (int it = 0; it < 12; ++it) {
        nfloat4 v = __builtin_nontemporal_load(xr + lane + (it << 6));
        s += (v.x + v.y) + (v.z + v.w);
    }
    if (lane < 16) {
        nfloat4 v = __builtin_nontemporal_load(xr + 768 + lane);
        s += (v.x + v.y) + (v.z + v.w);
    }
#pragma unroll
    for (int off = 32; off > 0; off >>= 1) s += __shfl_down(s, off);
    if (lane == 0) y[row] = s * (1.0f / 3136.0f);
}

// ---------------------------------------------------------------------------
// Kernel 2: fc1 — h = gelu(y @ W1). Grid (16,32)=512 blocks, 32 cols/block,
// 32-way split-K. jc==0 blocks seed AB with the biases.
// MLP pair measured (bisect R17): 10.5 us total — launch-floor bound.
// ---------------------------------------------------------------------------
__global__ __launch_bounds__(256) void fc1_kernel(const float* __restrict__ y,
                                                  const float* __restrict__ W1,
                                                  const float* __restrict__ bA,
                                                  const float* __restrict__ bB,
                                                  float* __restrict__ h,
                                                  float* __restrict__ AB) {
    const int jc = blockIdx.x;   // 0..15
    const int b  = blockIdx.y;   // 0..31
    const int t  = threadIdx.x;

    __shared__ float   sy[NC];
    __shared__ nfloat4 part[256];
    __shared__ nfloat4 spart[64];
    for (int i = t; i < NC; i += 256) sy[i] = y[b * NC + i];
    __syncthreads();

    const int lane8 = t & 7;
    const int j0 = jc * 32 + lane8 * 4;
    const int ks = (t >> 3) * 32;            // 32 K-slices of 32 rows

    nfloat4 acc0 = {0.f, 0.f, 0.f, 0.f};
    nfloat4 acc1 = {0.f, 0.f, 0.f, 0.f};
    const float* wbase = W1 + (size_t)ks * NHID + j0;
#pragma unroll 8
    for (int c = 0; c < 32; c += 2) {
        nfloat4 w0 = *(const nfloat4*)(wbase + (size_t)(c + 0) * NHID);
        nfloat4 w1 = *(const nfloat4*)(wbase + (size_t)(c + 1) * NHID);
        acc0 += sy[ks + c + 0] * w0;
        acc1 += sy[ks + c + 1] * w1;
    }
    part[t] = acc0 + acc1;
    __syncthreads();
    if (t < 64) spart[t] = part[t] + part[t + 64] + part[t + 128] + part[t + 192];
    __syncthreads();
    if (t < 8) {
        nfloat4 s = spart[t];
#pragma unroll
        for (int g = 1; g < 8; ++g) s += spart[g * 8 + t];
        float* hp = h + b * NHID + jc * 32 + t * 4;
        hp[0] = gelu_exact(s.x);
        hp[1] = gelu_exact(s.y);
        hp[2] = gelu_exact(s.z);
        hp[3] = gelu_exact(s.w);
    }
    if (jc == 0) {                       // seed AB with biases
        if (t < NH)                         AB[b * 128 + t]      = bA[t];
        else if (t >= 64 && t < 64 + NW)    AB[b * 128 + t]      = bB[t - 64];
    }
}

// ---------------------------------------------------------------------------
// Kernel 3: fc2+ab fused. Grid (32,32)=1024 blocks, 32 yp-cols/block.
// Computes 32 gelu(h@W2) values into LDS, dots them against the matching
// 32 rows of WA/WB, atomicAdds the 112-element partial into AB.
// ---------------------------------------------------------------------------
__global__ __launch_bounds__(256) void fc2ab_kernel(const float* __restrict__ h,
                                                    const float* __restrict__ W2,
                                                    const float* __restrict__ WA,
                                                    const float* __restrict__ WB,
                                                    float* __restrict__ AB) {
    const int cc = blockIdx.x;   // 0..31
    const int b  = blockIdx.y;
    const int t  = threadIdx.x;

    __shared__ float   sh[NHID];
    __shared__ nfloat4 part[256];
    __shared__ nfloat4 spart[64];
    __shared__ float   ypl[32];
    for (int i = t; i < NHID; i += 256) sh[i] = h[b * NHID + i];
    __syncthreads();

    const int lane8 = t & 7;
    const int c0 = cc * 32 + lane8 * 4;
    const int js = (t >> 3) * 16;            // 32 K-slices of 16 rows

    nfloat4 acc0 = {0.f, 0.f, 0.f, 0.f};
    nfloat4 acc1 = {0.f, 0.f, 0.f, 0.f};
    const float* wbase = W2 + (size_t)js * NC + c0;
#pragma unroll 8
    for (int jj = 0; jj < 16; jj += 2) {
        nfloat4 w0 = *(const nfloat4*)(wbase + (size_t)(jj + 0) * NC);
        nfloat4 w1 = *(const nfloat4*)(wbase + (size_t)(jj + 1) * NC);
        acc0 += sh[js + jj + 0] * w0;
        acc1 += sh[js + jj + 1] * w1;
    }
    part[t] = acc0 + acc1;
    __syncthreads();
    if (t < 64) spart[t] = part[t] + part[t + 64] + part[t + 128] + part[t + 192];
    __syncthreads();
    if (t < 8) {
        nfloat4 s = spart[t];
        #pragma unroll
        for (int g = 1; g < 8; ++g) s += spart[g * 8 + t];
        ypl[t * 4 + 0] = gelu_exact(s.x);
        ypl[t * 4 + 1] = gelu_exact(s.y);
        ypl[t * 4 + 2] = gelu_exact(s.z);
        ypl[t * 4 + 3] = gelu_exact(s.w);
    }
    __syncthreads();

    // ab partial over rows [cc*32, cc*32+32)
    if (t < 112) {
        const bool isA = t < 56;
        const int  i   = isA ? t : t - 56;
        const float* w = (isA ? WA : WB) + (size_t)(cc * 32) * 56 + i;
        float a0 = 0.f, a1 = 0.f, a2 = 0.f, a3 = 0.f;
#pragma unroll 4
        for (int c = 0; c < 32; c += 4) {
            a0 += ypl[c + 0] * w[(size_t)(c + 0) * 56];
            a1 += ypl[c + 1] * w[(size_t)(c + 1) * 56];
            a2 += ypl[c + 2] * w[(size_t)(c + 2) * 56];
            a3 += ypl[c + 3] * w[(size_t)(c + 3) * 56];
        }
        atomicAdd(&AB[b * 128 + (isA ? i : 64 + i)], (a0 + a1) + (a2 + a3));
    }
}

// ---------------------------------------------------------------------------
// Kernel 4: bcast v4 — wave-monotonic NT stores, 512 blocks. MEASURED ~79 us;
// write ceiling across 5 tested shapes (bisect-proven R11/R16).
// ---------------------------------------------------------------------------
__global__ __launch_bounds__(256) void bcast_kernel(const float* __restrict__ AB,
                                                    float* __restrict__ out) {
    const int blk = blockIdx.x;      // 32 b * 16 chunks = 512
    const int b = blk >> 4;
    const int chunk = blk & 15;      // 64 channels per chunk
    const int t = threadIdx.x;

    __shared__ float sA[NH];
    __shared__ float sB[NW];
    __shared__ nfloat4 smap[HW4 + 64];   // 848 entries
    if (t < NH) sA[t] = AB[b * 128 + t];
    else if (t >= 64 && t < 64 + NW) sB[t - 64] = AB[b * 128 + t];
    __syncthreads();

    for (int idx = t; idx < HW4 + 64; idx += 256) {
        const int p  = (idx >= HW4) ? idx - HW4 : idx;
        const int r  = p / 14;
        const int cb = (p - r * 14) * 4;
        const float a = sA[r];
        nfloat4 q;
        q.x = 1.0f / (1.0f + expf(-(a * sB[cb + 0])));
        q.y = 1.0f / (1.0f + expf(-(a * sB[cb + 1])));
        q.z = 1.0f / (1.0f + expf(-(a * sB[cb + 2])));
        q.w = 1.0f / (1.0f + expf(-(a * sB[cb + 3])));
        smap[idx] = q;
    }
    __syncthreads();

    const int w    = t >> 6;         // wave 0..3 -> 16 channels each
    const int lane = t & 63;
    nfloat4* op = (nfloat4*)out +
                  ((size_t)b * NC + (size_t)chunk * 64 + (size_t)w * 16) * HW4;
    int pos = 0;                      // (it*64) % 784
#pragma unroll 7
    for (int it = 0; it < 196; ++it) {
        __builtin_nontemporal_store(smap[pos + lane], &op[it * 64 + lane]);
        pos += 64;
        if (pos >= HW4) pos -= HW4;
    }
}

// ---------------------------------------------------------------------------
extern "C" void kernel_launch(void* const* d_in, const int* in_sizes, int n_in,
                              void* d_out, int out_size, void* d_ws, size_t ws_size,
                              hipStream_t stream) {
    const float* x  = (const float*)d_in[0];
    const float* W1 = (const float*)d_in[1];
    const float* W2 = (const float*)d_in[2];
    const float* WA = (const float*)d_in[3];
    const float* bA = (const float*)d_in[4];
    const float* WB = (const float*)d_in[5];
    const float* bB = (const float*)d_in[6];
    float* out = (float*)d_out;

    float* y  = (float*)d_ws;            // BATCH*NC floats
    float* h  = y + BATCH * NC;          // BATCH*NHID floats
    float* AB = h + BATCH * NHID;        // BATCH*128 floats

    gap_kernel<<<BATCH * NC / 4, 256, 0, stream>>>(x, y);
    fc1_kernel<<<dim3(16, BATCH), 256, 0, stream>>>(y, W1, bA, bB, h, AB);
    fc2ab_kernel<<<dim3(32, BATCH), 256, 0, stream>>>(h, W2, WA, WB, AB);
    bcast_kernel<<<512, 256, 0, stream>>>(AB, out);
}